// Round 1
// baseline (56.966 us; speedup 1.0000x reference)
//
#include <hip/hip_runtime.h>

#define NR 5000
#define NRM1 4999
#define W 640
#define NBLK 2500          // balanced row pairs: block b handles rows b and 4998-b
#define PCOUNT 12497500.0f

// ---------------- Kernel 1: gather z = x[rows, cols] ----------------
__global__ void gather_z(const float* __restrict__ x,
                         const int* __restrict__ centers,
                         float* __restrict__ z) {
    int t = blockIdx.x * blockDim.x + threadIdx.x;
    if (t < NR) {
        int r = centers[2 * t];
        int c = centers[2 * t + 1];
        z[t] = x[r * W + c];
    }
}

// ---------------- Kernel 2: per-pair loss, per-block partial sums ----------------
// Block b processes row r1 = b (j in [b+1, 4999]) and row r2 = 4998-b (if r2 > r1).
// Row r1 has 4999-b elements, row r2 has b+1 elements => exactly 5000 per block.
// gt reads are contiguous within each row (coalesced). z is staged in LDS.
__global__ __launch_bounds__(256) void pair_loss(const float* __restrict__ gt,
                                                 const float* __restrict__ z,
                                                 float* __restrict__ partials) {
    __shared__ float sz[NR];
    __shared__ float wsum[4];

    for (int t = threadIdx.x; t < NR; t += 256) sz[t] = z[t];
    __syncthreads();

    float acc = 0.0f;
    const int b = blockIdx.x;
    const int r1 = b;
    const int r2 = NR - 2 - b;

    #pragma unroll 1
    for (int pass = 0; pass < 2; ++pass) {
        const int r = (pass == 0) ? r1 : r2;
        if (pass == 1 && r2 <= r1) break;
        // triu flat offset of row r: r*(NR-1) - r*(r-1)/2  (fits in int32)
        const int off = r * NRM1 - (r * (r - 1)) / 2;
        const float zr = sz[r];
        const int len = NRM1 - r;          // j runs r+1 .. NR-1
        const float* __restrict__ gtr = gt + off;
        for (int t = threadIdx.x; t < len; t += 256) {
            const int j = r + 1 + t;
            const float d = zr - sz[j];
            const float g = gtr[t];
            // mask = |g| with g in {-1,0,1}: select instead of multiply-by-mask
            const float loss = (g != 0.0f) ? log1pf(__expf(-g * d)) : d * d;
            acc += loss;
        }
    }

    // deterministic block reduction: wave shuffle tree + LDS across 4 waves
    for (int o = 32; o > 0; o >>= 1) acc += __shfl_down(acc, o, 64);
    const int wid = threadIdx.x >> 6;
    const int lane = threadIdx.x & 63;
    if (lane == 0) wsum[wid] = acc;
    __syncthreads();
    if (threadIdx.x == 0)
        partials[blockIdx.x] = (wsum[0] + wsum[1]) + (wsum[2] + wsum[3]);
}

// ---------------- Kernel 3: deterministic final reduce ----------------
__global__ __launch_bounds__(256) void final_reduce(const float* __restrict__ partials,
                                                    float* __restrict__ out) {
    __shared__ float wsum[4];
    float acc = 0.0f;
    for (int t = threadIdx.x; t < NBLK; t += 256) acc += partials[t];
    for (int o = 32; o > 0; o >>= 1) acc += __shfl_down(acc, o, 64);
    const int wid = threadIdx.x >> 6;
    const int lane = threadIdx.x & 63;
    if (lane == 0) wsum[wid] = acc;
    __syncthreads();
    if (threadIdx.x == 0)
        out[0] = ((wsum[0] + wsum[1]) + (wsum[2] + wsum[3])) / PCOUNT;
}

extern "C" void kernel_launch(void* const* d_in, const int* in_sizes, int n_in,
                              void* d_out, int out_size, void* d_ws, size_t ws_size,
                              hipStream_t stream) {
    const float* x       = (const float*)d_in[0];   // (480,640) f32
    const float* gt      = (const float*)d_in[1];   // (P,) f32
    const int*   centers = (const int*)d_in[2];     // (5000,2) int32
    float* out = (float*)d_out;                     // scalar f32

    float* z        = (float*)d_ws;                 // 5000 floats
    float* partials = z + NR;                       // 2500 floats

    gather_z<<<(NR + 255) / 256, 256, 0, stream>>>(x, centers, z);
    pair_loss<<<NBLK, 256, 0, stream>>>(gt, z, partials);
    final_reduce<<<1, 256, 0, stream>>>(partials, out);
}

// Round 2
// 26.685 us; speedup vs baseline: 2.1348x; 2.1348x over previous
//
#include <hip/hip_runtime.h>

#define NR 5000
#define NRM1 4999
#define W 640
#define NBLK 2500          // balanced row pairs: block b handles rows b and 4998-b
#define PCOUNT 12497500.0f

// ---------------- Kernel 1: gather z = x[rows, cols] ----------------
__global__ void gather_z(const float* __restrict__ x,
                         const int* __restrict__ centers,
                         float* __restrict__ z) {
    int t = blockIdx.x * blockDim.x + threadIdx.x;
    if (t < NR) {
        int r = centers[2 * t];
        int c = centers[2 * t + 1];
        z[t] = x[r * W + c];
    }
}

// softplus(-g*d) when g=±1, else d^2.  Hardware trans pipe: v_exp_f32+v_log_f32.
// |d| <= ~10 so exp/log never overflow; g==0 path computes log(2) harmlessly.
__device__ __forceinline__ float loss_elem(float zr, float zj, float g) {
    float d = zr - zj;
    float sp = __logf(1.0f + __expf(-g * d));
    return (g != 0.0f) ? sp : d * d;
}

// ---------------- Kernel 2: per-pair loss, per-block partial sums ----------------
// Block b processes row r1 = b (len 4999-b) and row r2 = 4998-b (len b+1):
// exactly 5000 elements per block. gt and z reads are contiguous (coalesced);
// z (20 KB) is L2-resident and broadcast across blocks — no LDS staging.
__global__ __launch_bounds__(256) void pair_loss(const float* __restrict__ gt,
                                                 const float* __restrict__ z,
                                                 float* __restrict__ partials) {
    __shared__ float wsum[4];
    const int b = blockIdx.x;

    float a0 = 0.0f, a1 = 0.0f, a2 = 0.0f, a3 = 0.0f;

    #pragma unroll 1
    for (int pass = 0; pass < 2; ++pass) {
        const int r = (pass == 0) ? b : (NR - 2 - b);
        if (pass == 1 && r <= b) break;
        const int off = r * NRM1 - (r * (r - 1)) / 2;   // triu row offset, fits i32
        const float zr = z[r];
        const int len = NRM1 - r;                        // j runs r+1 .. NR-1
        const float* __restrict__ gtr  = gt + off;
        const float* __restrict__ zrow = z + r + 1;

        int t = threadIdx.x;
        // main: 4 independent load pairs per iteration (MLP + 4 acc chains)
        for (; t + 768 < len; t += 1024) {
            const float g0 = gtr[t];
            const float g1 = gtr[t + 256];
            const float g2 = gtr[t + 512];
            const float g3 = gtr[t + 768];
            const float z0 = zrow[t];
            const float z1 = zrow[t + 256];
            const float z2 = zrow[t + 512];
            const float z3 = zrow[t + 768];
            a0 += loss_elem(zr, z0, g0);
            a1 += loss_elem(zr, z1, g1);
            a2 += loss_elem(zr, z2, g2);
            a3 += loss_elem(zr, z3, g3);
        }
        // tail
        for (; t < len; t += 256) {
            a0 += loss_elem(zr, zrow[t], gtr[t]);
        }
    }

    float acc = (a0 + a1) + (a2 + a3);

    // deterministic block reduction: wave shuffle tree + LDS across 4 waves
    for (int o = 32; o > 0; o >>= 1) acc += __shfl_down(acc, o, 64);
    const int wid = threadIdx.x >> 6;
    const int lane = threadIdx.x & 63;
    if (lane == 0) wsum[wid] = acc;
    __syncthreads();
    if (threadIdx.x == 0)
        partials[blockIdx.x] = (wsum[0] + wsum[1]) + (wsum[2] + wsum[3]);
}

// ---------------- Kernel 3: deterministic final reduce ----------------
__global__ __launch_bounds__(256) void final_reduce(const float* __restrict__ partials,
                                                    float* __restrict__ out) {
    __shared__ float wsum[4];
    float acc = 0.0f;
    for (int t = threadIdx.x; t < NBLK; t += 256) acc += partials[t];
    for (int o = 32; o > 0; o >>= 1) acc += __shfl_down(acc, o, 64);
    const int wid = threadIdx.x >> 6;
    const int lane = threadIdx.x & 63;
    if (lane == 0) wsum[wid] = acc;
    __syncthreads();
    if (threadIdx.x == 0)
        out[0] = ((wsum[0] + wsum[1]) + (wsum[2] + wsum[3])) / PCOUNT;
}

extern "C" void kernel_launch(void* const* d_in, const int* in_sizes, int n_in,
                              void* d_out, int out_size, void* d_ws, size_t ws_size,
                              hipStream_t stream) {
    const float* x       = (const float*)d_in[0];   // (480,640) f32
    const float* gt      = (const float*)d_in[1];   // (P,) f32
    const int*   centers = (const int*)d_in[2];     // (5000,2) int32
    float* out = (float*)d_out;                     // scalar f32

    float* z        = (float*)d_ws;                 // 5000 floats
    float* partials = z + NR;                       // 2500 floats

    gather_z<<<(NR + 255) / 256, 256, 0, stream>>>(x, centers, z);
    pair_loss<<<NBLK, 256, 0, stream>>>(gt, z, partials);
    final_reduce<<<1, 256, 0, stream>>>(partials, out);
}